// Round 1
// 140.622 us; speedup vs baseline: 1.0486x; 1.0486x over previous
//
#include <hip/hip_runtime.h>
#include <math.h>

// Problem constants (B,N,C fixed by the reference setup).
#define BB 16
#define NN 2048
#define CC 64
#define TPB 256
#define MROWS 16          // pruned rows per block (4 waves x 4 rows)
#define RPW 4             // rows per wave
#define E_CONST 2.71828182845904523536f

// ---------------------------------------------------------------------------
// K_pre: zero the A accumulator (d_out) everywhere; blocks 0..BB-1 also run
// ballot-based kept/pruned compaction for batch b and zero S[b,:].
// ---------------------------------------------------------------------------
__global__ __launch_bounds__(TPB) void k_pre(const float* __restrict__ keep,
                                             float* __restrict__ outz,
                                             float* __restrict__ S,
                                             int* __restrict__ cntP,
                                             int* __restrict__ cntK,
                                             int* __restrict__ listP,
                                             int* __restrict__ listK) {
    const int tid = threadIdx.x, lane = tid & 63;

    float4* o4 = (float4*)outz + (size_t)blockIdx.x * 1024;
    float4 z = {0.0f, 0.0f, 0.0f, 0.0f};
#pragma unroll
    for (int i = 0; i < 4; ++i) o4[i * TPB + tid] = z;

    const int b = blockIdx.x;
    if (b >= BB) return;

    __shared__ int cP, cK;
    if (tid == 0) { cP = 0; cK = 0; }
    __syncthreads();
    for (int i = tid; i < NN; i += TPB) S[b * NN + i] = 0.0f;
    const unsigned long long lt = (lane == 63) ? 0x7fffffffffffffffull
                                               : ((1ull << lane) - 1ull);
#pragma unroll
    for (int it = 0; it < NN / TPB; ++it) {
        int n = it * TPB + tid;
        bool kp = keep[b * NN + n] != 0.0f;
        unsigned long long mk = __ballot(kp);
        int nk = __popcll(mk);
        int bk = 0, bp = 0;
        if (lane == 0) {
            bk = atomicAdd(&cK, nk);
            bp = atomicAdd(&cP, 64 - nk);
        }
        bk = __shfl(bk, 0); bp = __shfl(bp, 0);
        int pk = __popcll(mk & lt);
        if (kp) listK[b * NN + bk + pk] = n;
        else    listP[b * NN + bp + (lane - pk)] = n;
    }
    __syncthreads();
    if (tid == 0) { cntP[b] = cP; cntK[b] = cK; }
}

// ---------------------------------------------------------------------------
// K_pre2 (R16 rewrite): ONE WAVE PER KEPT TOKEN.
//  - old version gathered 16B/lane from 64 different token rows per load
//    instruction (64-way uncoalesced) on a 128-block grid: suspected hidden
//    20-40us latency sink.
//  - now: wave loads x[tok*64+lane] (one coalesced 256B dword load), norm via
//    6x shfl_xor, then one transposed scatter store into colM (lanes 0..3
//    form a contiguous float4 of k-quad 0; adjacent colp waves merge lines
//    in L2).
//  - 1-D grid, b = id&15 -> same XCD pinning as k_argmax, so colM is written
//    into the L2 that consumes it.
//  - zero-fills [K, K+128): the adaptive tiler in k_argmax never reads past
//    colp = K+127. (K>1920 cannot occur with Bernoulli(0.5) x 2048.)
// ---------------------------------------------------------------------------
__global__ __launch_bounds__(TPB) void k_pre2(const float* __restrict__ x,
                                              const int* __restrict__ cntK,
                                              const int* __restrict__ listK,
                                              float* __restrict__ colMf) {
    const int b    = blockIdx.x & 15;
    const int seg  = blockIdx.x >> 4;          // 0..63
    const int lane = threadIdx.x & 63;
    const int wid  = threadIdx.x >> 6;
    const int wave = seg * 4 + wid;            // 0..255 per batch
    const int K    = cntK[b];
    const int Kend = min(NN, K + 128);

    const float* xb = x + (size_t)b * NN * CC;
    float* cf = colMf + (size_t)b * 16 * NN * 4;   // batch's [16][NN] float4

    for (int colp = wave; colp < Kend; colp += 256) {
        float v = 0.0f;
        if (colp < K) {
            int tok = listK[b * NN + colp];
            float xv = xb[(size_t)tok * CC + lane];
            float sq = xv * xv;
#pragma unroll
            for (int off = 32; off; off >>= 1) sq += __shfl_xor(sq, off, 64);
            v = xv / (sqrtf(sq) + 1e-6f);
        }
        // float4 element (k4 = lane>>2, colp), component lane&3
        cf[((size_t)(lane >> 2) * NN + colp) * 4 + (lane & 3)] = v;
    }
}

// ---------------------------------------------------------------------------
// K3: GEMM-argmax. R16 change: adaptive column tiles (512/256/128) instead of
// fixed 512. K ~ 1024 +/- 23, so ceil(K/512) rounds up to 3 tiles for ~half
// the batches (a full 512-col tile for <=70 real columns) -> ~20% padded FMA
// work AND a 1.5x per-XCD imbalance (the measured 26% occupancy tail).
// template<int J> keeps each body fully unrolled/register-blocked; J=8 is the
// exact R9/R13 inner loop. Tie mask is now 64-bit with global bit = colp>>6.
//  - acc[4][8] + cv[8] register shape preserved in the J=8 path (VGPR 60).
//  - unroll 2 (unroll 4 regressed: R12). No hand dbuf/SGPR tricks (R6-R11).
// ---------------------------------------------------------------------------
template <int J>
__device__ __forceinline__ void tile_body(const float4* __restrict__ x4,
                                          const float4* __restrict__ cm,
                                          const int* rtok, int cstart, int K,
                                          int lane, float* tmax,
                                          unsigned long long* msk) {
    float acc[RPW][J];
#pragma unroll
    for (int r = 0; r < RPW; ++r)
#pragma unroll
        for (int j = 0; j < J; ++j) acc[r][j] = 0.0f;

#pragma unroll 2
    for (int k4 = 0; k4 < 16; ++k4) {
        float4 rv[RPW];
#pragma unroll
        for (int r = 0; r < RPW; ++r)           // wave-uniform 16B loads
            rv[r] = x4[(size_t)rtok[r] * 16 + k4];
        const float4* cmk = cm + (size_t)k4 * NN + cstart + lane;
        float4 cv[J];
#pragma unroll
        for (int j = 0; j < J; ++j)             // coalesced b128 streams
            cv[j] = cmk[j * 64];
#pragma unroll
        for (int r = 0; r < RPW; ++r)
#pragma unroll
            for (int j = 0; j < J; ++j)
                acc[r][j] = fmaf(rv[r].x, cv[j].x,
                            fmaf(rv[r].y, cv[j].y,
                            fmaf(rv[r].z, cv[j].z,
                            fmaf(rv[r].w, cv[j].w, acc[r][j]))));
    }

    const int cb0 = cstart >> 6;
#pragma unroll
    for (int r = 0; r < RPW; ++r)
#pragma unroll
        for (int j = 0; j < J; ++j) {
            int colp = cstart + j * 64 + lane;
            float s = (colp < K) ? acc[r][j] : -1.0e30f;
            unsigned long long bit = 1ull << (cb0 + j);
            if (s > tmax[r])       { tmax[r] = s; msk[r] = bit; }
            else if (s == tmax[r])  msk[r] |= bit;
        }
}

__global__ __launch_bounds__(TPB, 4) void k_argmax(
    const float* __restrict__ x,      // [B,N,C]
    const float4* __restrict__ colM,  // [B,16,N] float4
    const int*   __restrict__ cntP,
    const int*   __restrict__ cntK,
    const int*   __restrict__ listP,
    const int*   __restrict__ listK,
    float* __restrict__ S,            // [B,N]   zeroed by k_pre
    float* __restrict__ A) {          // [B,N,C] zeroed by k_pre; aliases d_out

    const int b    = blockIdx.x & 15;
    const int tile = blockIdx.x >> 4;
    const int P = cntP[b], K = cntK[b];
    const int base = tile * MROWS;
    if (base >= P) return;

    const int tid = threadIdx.x;
    const int wid = tid >> 6;
    const int lane = tid & 63;

    int rtok[RPW];
#pragma unroll
    for (int r = 0; r < RPW; ++r) {
        int rid = base + wid * RPW + r;
        int tok = (rid < P) ? listP[b * NN + rid] : 0;
        rtok[r] = __builtin_amdgcn_readfirstlane(tok);
    }
    const float4* x4 = (const float4*)(x + (size_t)b * NN * CC);
    const float4* cm = colM + (size_t)b * 16 * NN;

    float              tmax[RPW];
    unsigned long long msk[RPW];
#pragma unroll
    for (int r = 0; r < RPW; ++r) { tmax[r] = -3.0e38f; msk[r] = 0ull; }

    // Adaptive tiling: full 512-col tiles while >384 cols remain, then one
    // 256 and/or one 128-col epilogue. Branches are wave-uniform (K uniform).
    int cstart = 0;
    while (cstart < K) {
        int rem = K - cstart;
        if (rem > 384) {
            tile_body<8>(x4, cm, rtok, cstart, K, lane, tmax, msk);
            cstart += 512;
        } else if (rem > 128) {
            tile_body<4>(x4, cm, rtok, cstart, K, lane, tmax, msk);
            cstart += 256;
        } else {
            tile_body<2>(x4, cm, rtok, cstart, K, lane, tmax, msk);
            cstart += 128;
        }
    }

    // ---- edge emission: per wave, per valid row ----
    int nvr = P - base - wid * RPW;
    for (int r = 0; r < RPW; ++r) {
        if (r >= nvr) break;
        float m = tmax[r];
#pragma unroll
        for (int off = 32; off; off >>= 1) m = fmaxf(m, __shfl_xor(m, off, 64));
        int src = rtok[r];
        float xv = x[(size_t)(b * NN + src) * CC + lane];
        float sq = xv * xv;
#pragma unroll
        for (int off = 32; off; off >>= 1) sq += __shfl_xor(sq, off, 64);
        float ivr = 1.0f / (sqrtf(sq) + 1e-6f);
        float wgt = expf(m * ivr);
        unsigned long long bal = __ballot(tmax[r] == m && msk[r] != 0ull);
        while (bal) {
            int sl = __ffsll(bal) - 1;
            bal &= bal - 1;
            unsigned long long mm = __shfl(msk[r], sl);
            while (mm) {
                int cb = __ffsll(mm) - 1;
                mm &= mm - 1;
                int colp = (cb << 6) + sl;
                int dst = listK[b * NN + colp];
                atomicAdd(&A[(size_t)(b * NN + dst) * CC + lane], wgt * xv);
                if (lane == 0) atomicAdd(&S[b * NN + dst], wgt);
            }
        }
    }
}

// ---------------------------------------------------------------------------
// K4: out = (e*x + A) / (e + S).  A aliases d_out (in-place), float4.
// ---------------------------------------------------------------------------
__global__ __launch_bounds__(TPB) void k_finalize(const float* __restrict__ x,
                                                  const float* __restrict__ S,
                                                  float* __restrict__ out) {
    int i = blockIdx.x * TPB + threadIdx.x;
    int row = i >> 4;
    float inv = 1.0f / (E_CONST + S[row]);
    float4 xv = ((const float4*)x)[i];
    float4 av = ((float4*)out)[i];
    float4 o;
    o.x = (xv.x * E_CONST + av.x) * inv;
    o.y = (xv.y * E_CONST + av.y) * inv;
    o.z = (xv.z * E_CONST + av.z) * inv;
    o.w = (xv.w * E_CONST + av.w) * inv;
    ((float4*)out)[i] = o;
}

// ---------------------------------------------------------------------------
extern "C" void kernel_launch(void* const* d_in, const int* in_sizes, int n_in,
                              void* d_out, int out_size, void* d_ws, size_t ws_size,
                              hipStream_t stream) {
    const float* x    = (const float*)d_in[0];
    const float* keep = (const float*)d_in[2];
    float* out = (float*)d_out;

    // ws: (reserved 128KB) | S 128KB | cnts 128B | listP 128KB | listK 128KB | colM 8MB
    char* ws = (char*)d_ws;
    float* S    = (float*)(ws + (128 << 10));
    int*   cntP = (int*)(ws + (256 << 10));
    int*   cntK = cntP + 16;
    int*   listP = (int*)(ws + (256 << 10) + 128);
    int*   listK = listP + BB * NN;
    float* colMf = (float*)(ws + (1 << 20));

    k_pre<<<512, TPB, 0, stream>>>(keep, out, S, cntP, cntK, listP, listK);

    // 1-D grid, b = id&15: colM written on the XCD that k_argmax reads it on.
    k_pre2<<<BB * 64, TPB, 0, stream>>>(x, cntK, listK, colMf);

    // 1-D grid: b = id & 15 (XCD pinning), tile = id >> 4.
    k_argmax<<<(NN / MROWS) * BB, TPB, 0, stream>>>(x, (const float4*)colMf,
                                                    cntP, cntK, listP, listK,
                                                    S, out);

    k_finalize<<<(BB * NN * CC / 4) / TPB, TPB, 0, stream>>>(x, S, out);
}